// Round 5
// baseline (1905.894 us; speedup 1.0000x reference)
//
#include <hip/hip_runtime.h>
#include <hip/hip_bf16.h>
#include <math.h>

// B=4, M=2048, D=512, H=8. Heads processed in groups of G (adaptive to ws_size; G=8 on this harness).

typedef __attribute__((ext_vector_type(8))) __bf16 bf16x8;
typedef __attribute__((ext_vector_type(4))) __bf16 bf16x4;
typedef __attribute__((ext_vector_type(4))) float f32x4;

#define MFMA16(a, b, c) __builtin_amdgcn_mfma_f32_16x16x32_bf16((a), (b), (c), 0, 0, 0)

__device__ __forceinline__ void g2l16(const void* g, void* l) {
  __builtin_amdgcn_global_load_lds((const __attribute__((address_space(1))) void*)g,
                                   (__attribute__((address_space(3))) void*)l, 16, 0, 0);
}

// ---------------- cast fp32 -> bf16 ----------------
__global__ void cast_bf16_k(const float* __restrict__ in, __bf16* __restrict__ out, int n4) {
  int i = blockIdx.x * blockDim.x + threadIdx.x;
  if (i >= n4) return;
  float4 f = reinterpret_cast<const float4*>(in)[i];
  bf16x4 o;
  o.x = (__bf16)f.x; o.y = (__bf16)f.y; o.z = (__bf16)f.z; o.w = (__bf16)f.w;
  reinterpret_cast<bf16x4*>(out)[i] = o;
}

// ---------------- RoPE tables, fp32 (faithful i-1 quirk) ----------------
__global__ void rope_tables_k(float* __restrict__ ct, float* __restrict__ st) {
  int idx = blockIdx.x * 256 + threadIdx.x;  // 2048*256
  int m = idx >> 8, j = idx & 255;
  float e = (-2.0f * ((float)j - 1.0f) / 512.0f) * 13.287712379549449f;  // log2(1e4)
  float theta = exp2f(e);
  float ang = (float)m * theta;
  float s, c;
  sincosf(ang, &s, &c);
  ct[idx] = c;
  st[idx] = s;
}

// ---------------- QKV projection (round-2 proven structure): z = which*G + hl ----------------
__global__ __launch_bounds__(256, 2) void qkv_gemm_k(
    const __bf16* __restrict__ Xb,
    const __bf16* __restrict__ Wqb, const __bf16* __restrict__ Wkb, const __bf16* __restrict__ Wvb,
    const float* __restrict__ ct, const float* __restrict__ st,
    __bf16* __restrict__ Q, __bf16* __restrict__ K, __bf16* __restrict__ V,
    int G, int lg, int h0) {
  const int z = blockIdx.z;
  const int which = z >> lg, hl = z & (G - 1);
  const int h = h0 + hl;
  const __bf16* W = (which == 0 ? Wqb : which == 1 ? Wkb : Wvb) + (size_t)h * 262144;
  __bf16* Out = (which == 0 ? Q : which == 1 ? K : V);

  const int mbase = blockIdx.x * 128;
  const int nbase = blockIdx.y * 128;

  __shared__ alignas(16) __bf16 As[128 * 64];
  __shared__ alignas(16) __bf16 Bs[128 * 64];

  const int tid = threadIdx.x;
  const int lane = tid & 63, wid = tid >> 6;
  const int wr = wid >> 1, wc = wid & 1;
  const int l15 = lane & 15, l4 = lane >> 4;

  f32x4 acc[4][4];
#pragma unroll
  for (int i = 0; i < 4; i++)
#pragma unroll
    for (int j = 0; j < 4; j++) acc[i][j] = f32x4{0.f, 0.f, 0.f, 0.f};

  for (int kt = 0; kt < 8; ++kt) {
    const int kb = kt * 64;
#pragma unroll
    for (int i = 0; i < 4; i++) {
      int chunk = i * 256 + tid;
      int row = chunk >> 3, col = (chunk & 7) * 8;
      g2l16(Xb + (size_t)(mbase + row) * 512 + kb + col, As + (i * 256 + (tid & ~63)) * 8);
    }
#pragma unroll
    for (int i = 0; i < 4; i++) {
      int chunk = i * 256 + tid;
      int row = chunk >> 3, col = (chunk & 7) * 8;
      g2l16(W + (size_t)(nbase + row) * 512 + kb + col, Bs + (i * 256 + (tid & ~63)) * 8);
    }
    __syncthreads();
#pragma unroll
    for (int kk = 0; kk < 2; ++kk) {
      bf16x8 a[4], b[4];
#pragma unroll
      for (int i = 0; i < 4; i++)
        a[i] = *reinterpret_cast<const bf16x8*>(As + (wr * 64 + i * 16 + l15) * 64 + kk * 32 + l4 * 8);
#pragma unroll
      for (int j = 0; j < 4; j++)
        b[j] = *reinterpret_cast<const bf16x8*>(Bs + (wc * 64 + j * 16 + l15) * 64 + kk * 32 + l4 * 8);
#pragma unroll
      for (int i = 0; i < 4; i++)
#pragma unroll
        for (int j = 0; j < 4; j++) acc[i][j] = MFMA16(a[i], b[j], acc[i][j]);
    }
    __syncthreads();
  }

  const bool dorope = (which < 2);
#pragma unroll
  for (int i = 0; i < 4; i++) {
#pragma unroll
    for (int j = 0; j < 4; j++) {
      const int col = nbase + wc * 64 + j * 16 + l15;
#pragma unroll
      for (int r = 0; r < 4; r++) {
        const int rowg = mbase + wr * 64 + i * 16 + l4 * 4 + r;
        const int b_ = rowg >> 11, m = rowg & 2047;
        float v = acc[i][j][r];
        if (dorope) {
          float pv = __shfl_xor(v, 1, 64);  // partner column (col^1) in lane^1
          float c = ct[m * 256 + (col >> 1)];
          float s = st[m * 256 + (col >> 1)];
          v = (col & 1) ? (v * c - pv * s) : (v * c + pv * s);
        }
        Out[(size_t)((b_ * G + hl) * 2048 + m) * 512 + col] = (__bf16)v;
      }
    }
  }
}

// ---------------- V transpose: [(b*G+hl)][m][d] -> [(b*G+hl)][d][m] ----------------
__global__ void transpose_v_k(const __bf16* __restrict__ V, __bf16* __restrict__ VT) {
  __shared__ __bf16 sm[32][33];
  const int bh = blockIdx.z;
  const int mb = blockIdx.x * 32, db = blockIdx.y * 32;
  const int tx = threadIdx.x, ty = threadIdx.y;  // 32 x 8
  const __bf16* Vg = V + (size_t)bh * (2048 * 512);
  __bf16* Tg = VT + (size_t)bh * (512 * 2048);
#pragma unroll
  for (int i = 0; i < 4; i++) sm[ty + i * 8][tx] = Vg[(size_t)(mb + ty + i * 8) * 512 + db + tx];
  __syncthreads();
#pragma unroll
  for (int i = 0; i < 4; i++) Tg[(size_t)(db + ty + i * 8) * 2048 + mb + tx] = sm[tx][ty + i * 8];
}

// ---------------- causal flash attention v5 ----------------
// 8 waves x 16 q-rows (QBLK=128), KBLK=32. Block = q-tile pair (p, 15-p) = 68 tiles,
// 256 blocks (1/CU), grid x = p*32+bh (same-bh blocks share an XCD, co-travel in kb).
// K: 3-buffer LDS, 2-deep prefetch, counted vmcnt(4) + RAW s_barrier (never drains).
// V: read directly from global VT per wave (32KB tile is L1-resident, shared by 8 waves).
__global__ __launch_bounds__(512, 2) void flash_attn_k(
    const __bf16* __restrict__ Q, const __bf16* __restrict__ K, const __bf16* __restrict__ VT,
    __bf16* __restrict__ O, int G, int lg) {  // O: [B, M, G*512] bf16
  const int xid = blockIdx.x;              // 0 .. 32G-1
  const int bh = xid & (4 * G - 1);        // same-bh -> same XCD (xid % 8 == bh % 8)
  const int p = xid >> (lg + 2);           // 0..7
  const int b = bh >> lg, hl = bh & (G - 1);
  const int tid = threadIdx.x, lane = tid & 63, wid = tid >> 6;
  const int l15 = lane & 15, l4 = lane >> 4;

  __shared__ alignas(16) __bf16 Ks[3][32 * 512];  // 96KB, 3-bit XOR chunk swizzle
  __shared__ alignas(16) __bf16 Ps[8][16 * 36];   // 9KB, padded wave-private P

  const __bf16* Kg = K + (size_t)bh * 2048 * 512;
  const __bf16* Tg = VT + (size_t)bh * 512 * 2048;
  const float scale = 0.04419417382415922f;  // 1/sqrt(512)

  for (int pp = 0; pp < 2; ++pp) {
    const int qt = pp ? (15 - p) : p;
    const int qw = qt * 128 + wid * 16;
    const __bf16* Qg = Q + ((size_t)bh * 2048 + qw) * 512;

    bf16x8 qf[16];
#pragma unroll
    for (int c = 0; c < 16; c++)
      qf[c] = *reinterpret_cast<const bf16x8*>(Qg + l15 * 512 + c * 32 + l4 * 8);

    f32x4 acc[32];
#pragma unroll
    for (int n = 0; n < 32; n++) acc[n] = f32x4{0.f, 0.f, 0.f, 0.f};
    float mrow[4] = {-INFINITY, -INFINITY, -INFINITY, -INFINITY};
    float lrow[4] = {0.f, 0.f, 0.f, 0.f};

    const int nt = 4 * qt + 4;  // >= 4

    // stage K tile kt2 into Ks[bufi] (4 g2l16 per wave)
    auto stageK = [&](int kt2, int bufi) {
#pragma unroll
      for (int i = 0; i < 4; i++) {
        int chunk = i * 512 + tid;
        int row = chunk >> 6, c16 = chunk & 63;
        g2l16(Kg + (size_t)(kt2 * 32 + row) * 512 + ((c16 ^ (row & 7)) << 3),
              &Ks[bufi][(i * 512 + (tid & ~63)) * 8]);
      }
    };

    // prologue: 2-deep prefetch
    stageK(0, 0);
    stageK(1, 1);
    asm volatile("s_waitcnt vmcnt(4)" ::: "memory");  // K[0] landed; K[1] in flight
    __builtin_amdgcn_sched_barrier(0);
    __builtin_amdgcn_s_barrier();
    __builtin_amdgcn_sched_barrier(0);

    int cur = 0;
    for (int kt = 0; kt < nt; ++kt) {
      const int kb = kt * 32;

      // S = Q K^T from Ks[cur]
      f32x4 sv0 = f32x4{0.f, 0.f, 0.f, 0.f}, sv1 = f32x4{0.f, 0.f, 0.f, 0.f};
      const __bf16* Kl = &Ks[cur][0];
      __builtin_amdgcn_s_setprio(1);
#pragma unroll
      for (int c = 0; c < 16; c++) {
        const int off = c * 32 + l4 * 8;
        const int r0 = l15, r1 = 16 + l15;
        bf16x8 b0 = *reinterpret_cast<const bf16x8*>(Kl + r0 * 512 + (off ^ ((r0 & 7) << 3)));
        bf16x8 b1 = *reinterpret_cast<const bf16x8*>(Kl + r1 * 512 + (off ^ ((r1 & 7) << 3)));
        sv0 = MFMA16(qf[c], b0, sv0);
        sv1 = MFMA16(qf[c], b1, sv1);
      }
      __builtin_amdgcn_s_setprio(0);

      // online softmax (defer-max THR=8); mask only in the diagonal band
      const bool band = (kt >= 4 * qt);
      float mx[4];
#pragma unroll
      for (int r = 0; r < 4; r++) {
        float s0 = sv0[r] * scale;
        float s1 = sv1[r] * scale;
        if (band) {
          const int qg = qw + l4 * 4 + r;
          if (kb + l15 > qg) s0 = -INFINITY;
          if (kb + 16 + l15 > qg) s1 = -INFINITY;
        }
        sv0[r] = s0; sv1[r] = s1;
        float m_ = fmaxf(s0, s1);
        m_ = fmaxf(m_, __shfl_xor(m_, 1, 64));
        m_ = fmaxf(m_, __shfl_xor(m_, 2, 64));
        m_ = fmaxf(m_, __shfl_xor(m_, 4, 64));
        m_ = fmaxf(m_, __shfl_xor(m_, 8, 64));
        mx[r] = m_;
      }
      bool need = (mx[0] > mrow[0] + 8.f) || (mx[1] > mrow[1] + 8.f) ||
                  (mx[2] > mrow[2] + 8.f) || (mx[3] > mrow[3] + 8.f);
      if (__any(need)) {
        float alpha[4];
#pragma unroll
        for (int r = 0; r < 4; r++) {
          float mn = fmaxf(mrow[r], mx[r]);
          alpha[r] = __expf(mrow[r] - mn);
          lrow[r] *= alpha[r];
          mrow[r] = mn;
        }
#pragma unroll
        for (int n = 0; n < 32; n++) {
#pragma unroll
          for (int r = 0; r < 4; r++) acc[n][r] *= alpha[r];
        }
      }
#pragma unroll
      for (int r = 0; r < 4; r++) {
        float p0 = __expf(sv0[r] - mrow[r]);
        float p1 = __expf(sv1[r] - mrow[r]);
        float rs = p0 + p1;
        rs += __shfl_xor(rs, 1, 64);
        rs += __shfl_xor(rs, 2, 64);
        rs += __shfl_xor(rs, 4, 64);
        rs += __shfl_xor(rs, 8, 64);
        lrow[r] += rs;
        __bf16* P = &Ps[wid][0];
        P[(l4 * 4 + r) * 36 + l15] = (__bf16)p0;
        P[(l4 * 4 + r) * 36 + 16 + l15] = (__bf16)p1;
      }
      bf16x8 pf = *reinterpret_cast<const bf16x8*>(&Ps[wid][0] + l15 * 36 + l4 * 8);

      // PV: V read directly from global VT (L1-shared across the 8 waves)
      __builtin_amdgcn_s_setprio(1);
#pragma unroll
      for (int n = 0; n < 32; n++) {
        bf16x8 vb = *reinterpret_cast<const bf16x8*>(Tg + (size_t)(n * 16 + l15) * 2048 + kb + l4 * 8);
        acc[n] = MFMA16(pf, vb, acc[n]);
      }
      __builtin_amdgcn_s_setprio(0);
      __builtin_amdgcn_sched_barrier(0);

      // stage K[kt+2] into the buffer freed at kt-1; counted wait keeps it in flight
      if (kt + 2 < nt) {
        stageK(kt + 2, cur == 0 ? 2 : cur - 1);  // (cur+2)%3
        asm volatile("s_waitcnt vmcnt(4)" ::: "memory");  // K[kt+1] landed
      } else {
        asm volatile("s_waitcnt vmcnt(0)" ::: "memory");
      }
      __builtin_amdgcn_sched_barrier(0);
      __builtin_amdgcn_s_barrier();
      __builtin_amdgcn_sched_barrier(0);
      cur = (cur == 2) ? 0 : cur + 1;
    }

    // epilogue: O[b, qg, hl*512 + d] = acc / l
#pragma unroll
    for (int r = 0; r < 4; r++) {
      const int qg = qw + l4 * 4 + r;
      const float inv = 1.0f / lrow[r];
      __bf16* Og = O + ((size_t)(b * 2048 + qg) * (512 * G) + hl * 512);
#pragma unroll
      for (int n = 0; n < 32; n++) Og[n * 16 + l15] = (__bf16)(acc[n][r] * inv);
    }
  }
}

// ---------------- output projection (per group, accumulating) ----------------
__global__ __launch_bounds__(256, 2) void out_gemm_k(
    const __bf16* __restrict__ A, const __bf16* __restrict__ Wo,
    const float* __restrict__ bias, float* __restrict__ Y, int G, int first) {
  const int AS = 512 * G;
  const int mbase = blockIdx.x * 128, nbase = blockIdx.y * 128;
  __shared__ alignas(16) __bf16 As[128 * 64];
  __shared__ alignas(16) __bf16 Bs[128 * 64];
  const int tid = threadIdx.x;
  const int lane = tid & 63, wid = tid >> 6;
  const int wr = wid >> 1, wc = wid & 1;
  const int l15 = lane & 15, l4 = lane >> 4;

  f32x4 acc[4][4];
#pragma unroll
  for (int i = 0; i < 4; i++)
#pragma unroll
    for (int j = 0; j < 4; j++) acc[i][j] = f32x4{0.f, 0.f, 0.f, 0.f};

  const int nkt = 8 * G;
  for (int kt = 0; kt < nkt; ++kt) {
    const int kb = kt * 64;
#pragma unroll
    for (int i = 0; i < 4; i++) {
      int chunk = i * 256 + tid;
      int row = chunk >> 3, col = (chunk & 7) * 8;
      g2l16(A + (size_t)(mbase + row) * AS + kb + col, As + (i * 256 + (tid & ~63)) * 8);
    }
#pragma unroll
    for (int i = 0; i < 4; i++) {
      int chunk = i * 256 + tid;
      int row = chunk >> 3, col = (chunk & 7) * 8;
      g2l16(Wo + (size_t)(nbase + row) * 4096 + kb + col, Bs + (i * 256 + (tid & ~63)) * 8);
    }
    __syncthreads();
#pragma unroll
    for (int kk = 0; kk < 2; ++kk) {
      bf16x8 a[4], b[4];
#pragma unroll
      for (int i = 0; i < 4; i++)
        a[i] = *reinterpret_cast<const bf16x8*>(As + (wr * 64 + i * 16 + l15) * 64 + kk * 32 + l4 * 8);
#pragma unroll
      for (int j = 0; j < 4; j++)
        b[j] = *reinterpret_cast<const bf16x8*>(Bs + (wc * 64 + j * 16 + l15) * 64 + kk * 32 + l4 * 8);
#pragma unroll
      for (int i = 0; i < 4; i++)
#pragma unroll
        for (int j = 0; j < 4; j++) acc[i][j] = MFMA16(a[i], b[j], acc[i][j]);
    }
    __syncthreads();
  }

#pragma unroll
  for (int i = 0; i < 4; i++) {
#pragma unroll
    for (int j = 0; j < 4; j++) {
      const int col = nbase + wc * 64 + j * 16 + l15;
#pragma unroll
      for (int r = 0; r < 4; r++) {
        const int row = mbase + wr * 64 + i * 16 + l4 * 4 + r;
        float prev = first ? bias[col] : Y[(size_t)row * 512 + col];
        Y[(size_t)row * 512 + col] = prev + acc[i][j][r];
      }
    }
  }
}

extern "C" void kernel_launch(void* const* d_in, const int* in_sizes, int n_in,
                              void* d_out, int out_size, void* d_ws, size_t ws_size,
                              hipStream_t stream) {
  (void)in_sizes; (void)n_in; (void)out_size;
  const float* x = (const float*)d_in[0];
  const float* wq = (const float*)d_in[1];
  const float* wk = (const float*)d_in[2];
  const float* wv = (const float*)d_in[3];
  const float* wo = (const float*)d_in[4];
  const float* bo = (const float*)d_in[5];
  float* y = (float*)d_out;

  char* base = (char*)d_ws;
  size_t off = 0;
  auto alloc = [&](size_t bytes) -> void* {
    void* p = base + off;
    off += (bytes + 255) & ~(size_t)255;
    return p;
  };
  __bf16* xb = (__bf16*)alloc((size_t)8192 * 512 * 2);
  __bf16* wqb = (__bf16*)alloc((size_t)8 * 512 * 512 * 2);
  __bf16* wkb = (__bf16*)alloc((size_t)8 * 512 * 512 * 2);
  __bf16* wvb = (__bf16*)alloc((size_t)8 * 512 * 512 * 2);
  __bf16* wob = (__bf16*)alloc((size_t)512 * 4096 * 2);
  float* ct = (float*)alloc((size_t)2048 * 256 * 4);
  float* st = (float*)alloc((size_t)2048 * 256 * 4);
  const size_t persist = off;

  // choose largest head-group G with persist + 4 * (G*4*2048*512*2) <= ws_size
  int G = 0, lg = 0;
  for (int g = 8, l = 3; g >= 1; g >>= 1, --l) {
    size_t T = ((size_t)g * 4 * 2048 * 512 * 2 + 255) & ~(size_t)255;
    if (persist + 4 * T <= ws_size) { G = g; lg = l; break; }
  }
  if (G == 0) return;

  size_t T = ((size_t)G * 4 * 2048 * 512 * 2 + 255) & ~(size_t)255;
  __bf16* Qb = (__bf16*)(base + persist);
  __bf16* Kb = (__bf16*)(base + persist + T);
  __bf16* Vb = (__bf16*)(base + persist + 2 * T);
  __bf16* VTb = (__bf16*)(base + persist + 3 * T);
  __bf16* Ob = Vb;  // V dead after transpose; O ([B,M,G*512]) reuses it

  cast_bf16_k<<<4096, 256, 0, stream>>>(x, xb, 1048576);
  cast_bf16_k<<<2048, 256, 0, stream>>>(wq, wqb, 524288);
  cast_bf16_k<<<2048, 256, 0, stream>>>(wk, wkb, 524288);
  cast_bf16_k<<<2048, 256, 0, stream>>>(wv, wvb, 524288);
  cast_bf16_k<<<2048, 256, 0, stream>>>(wo, wob, 524288);
  rope_tables_k<<<2048, 256, 0, stream>>>(ct, st);

  for (int h0 = 0; h0 < 8; h0 += G) {
    qkv_gemm_k<<<dim3(64, 4, 3 * G), 256, 0, stream>>>(xb, wqb, wkb, wvb, ct, st,
                                                       Qb, Kb, Vb, G, lg, h0);
    transpose_v_k<<<dim3(64, 16, 4 * G), dim3(32, 8), 0, stream>>>(Vb, VTb);
    flash_attn_k<<<dim3(32 * G), 512, 0, stream>>>(Qb, Kb, VTb, Ob, G, lg);
    out_gemm_k<<<dim3(64, 4), 256, 0, stream>>>(Ob, wob + h0 * 512, bo, y, G, h0 == 0);
  }
}

// Round 6
// 1302.449 us; speedup vs baseline: 1.4633x; 1.4633x over previous
//
#include <hip/hip_runtime.h>
#include <hip/hip_bf16.h>
#include <math.h>

// B=4, M=2048, D=512, H=8. Heads processed in groups of G (adaptive to ws_size; G=8 on this harness).

typedef __attribute__((ext_vector_type(8))) __bf16 bf16x8;
typedef __attribute__((ext_vector_type(4))) __bf16 bf16x4;
typedef __attribute__((ext_vector_type(4))) float f32x4;

#define MFMA16(a, b, c) __builtin_amdgcn_mfma_f32_16x16x32_bf16((a), (b), (c), 0, 0, 0)

__device__ __forceinline__ void g2l16(const void* g, void* l) {
  __builtin_amdgcn_global_load_lds((const __attribute__((address_space(1))) void*)g,
                                   (__attribute__((address_space(3))) void*)l, 16, 0, 0);
}

// ---------------- cast fp32 -> bf16 ----------------
__global__ void cast_bf16_k(const float* __restrict__ in, __bf16* __restrict__ out, int n4) {
  int i = blockIdx.x * blockDim.x + threadIdx.x;
  if (i >= n4) return;
  float4 f = reinterpret_cast<const float4*>(in)[i];
  bf16x4 o;
  o.x = (__bf16)f.x; o.y = (__bf16)f.y; o.z = (__bf16)f.z; o.w = (__bf16)f.w;
  reinterpret_cast<bf16x4*>(out)[i] = o;
}

// ---------------- RoPE tables, fp32 (faithful i-1 quirk) ----------------
__global__ void rope_tables_k(float* __restrict__ ct, float* __restrict__ st) {
  int idx = blockIdx.x * 256 + threadIdx.x;  // 2048*256
  int m = idx >> 8, j = idx & 255;
  float e = (-2.0f * ((float)j - 1.0f) / 512.0f) * 13.287712379549449f;  // log2(1e4)
  float theta = exp2f(e);
  float ang = (float)m * theta;
  float s, c;
  sincosf(ang, &s, &c);
  ct[idx] = c;
  st[idx] = s;
}

// ---------------- QKV projection (round-2 proven structure): z = which*G + hl ----------------
__global__ __launch_bounds__(256, 2) void qkv_gemm_k(
    const __bf16* __restrict__ Xb,
    const __bf16* __restrict__ Wqb, const __bf16* __restrict__ Wkb, const __bf16* __restrict__ Wvb,
    const float* __restrict__ ct, const float* __restrict__ st,
    __bf16* __restrict__ Q, __bf16* __restrict__ K, __bf16* __restrict__ V,
    int G, int lg, int h0) {
  const int z = blockIdx.z;
  const int which = z >> lg, hl = z & (G - 1);
  const int h = h0 + hl;
  const __bf16* W = (which == 0 ? Wqb : which == 1 ? Wkb : Wvb) + (size_t)h * 262144;
  __bf16* Out = (which == 0 ? Q : which == 1 ? K : V);

  const int mbase = blockIdx.x * 128;
  const int nbase = blockIdx.y * 128;

  __shared__ alignas(16) __bf16 As[128 * 64];
  __shared__ alignas(16) __bf16 Bs[128 * 64];

  const int tid = threadIdx.x;
  const int lane = tid & 63, wid = tid >> 6;
  const int wr = wid >> 1, wc = wid & 1;
  const int l15 = lane & 15, l4 = lane >> 4;

  f32x4 acc[4][4];
#pragma unroll
  for (int i = 0; i < 4; i++)
#pragma unroll
    for (int j = 0; j < 4; j++) acc[i][j] = f32x4{0.f, 0.f, 0.f, 0.f};

  for (int kt = 0; kt < 8; ++kt) {
    const int kb = kt * 64;
#pragma unroll
    for (int i = 0; i < 4; i++) {
      int chunk = i * 256 + tid;
      int row = chunk >> 3, col = (chunk & 7) * 8;
      g2l16(Xb + (size_t)(mbase + row) * 512 + kb + col, As + (i * 256 + (tid & ~63)) * 8);
    }
#pragma unroll
    for (int i = 0; i < 4; i++) {
      int chunk = i * 256 + tid;
      int row = chunk >> 3, col = (chunk & 7) * 8;
      g2l16(W + (size_t)(nbase + row) * 512 + kb + col, Bs + (i * 256 + (tid & ~63)) * 8);
    }
    __syncthreads();
#pragma unroll
    for (int kk = 0; kk < 2; ++kk) {
      bf16x8 a[4], b[4];
#pragma unroll
      for (int i = 0; i < 4; i++)
        a[i] = *reinterpret_cast<const bf16x8*>(As + (wr * 64 + i * 16 + l15) * 64 + kk * 32 + l4 * 8);
#pragma unroll
      for (int j = 0; j < 4; j++)
        b[j] = *reinterpret_cast<const bf16x8*>(Bs + (wc * 64 + j * 16 + l15) * 64 + kk * 32 + l4 * 8);
#pragma unroll
      for (int i = 0; i < 4; i++)
#pragma unroll
        for (int j = 0; j < 4; j++) acc[i][j] = MFMA16(a[i], b[j], acc[i][j]);
    }
    __syncthreads();
  }

  const bool dorope = (which < 2);
#pragma unroll
  for (int i = 0; i < 4; i++) {
#pragma unroll
    for (int j = 0; j < 4; j++) {
      const int col = nbase + wc * 64 + j * 16 + l15;
#pragma unroll
      for (int r = 0; r < 4; r++) {
        const int rowg = mbase + wr * 64 + i * 16 + l4 * 4 + r;
        const int b_ = rowg >> 11, m = rowg & 2047;
        float v = acc[i][j][r];
        if (dorope) {
          float pv = __shfl_xor(v, 1, 64);  // partner column (col^1) in lane^1
          float c = ct[m * 256 + (col >> 1)];
          float s = st[m * 256 + (col >> 1)];
          v = (col & 1) ? (v * c - pv * s) : (v * c + pv * s);
        }
        Out[(size_t)((b_ * G + hl) * 2048 + m) * 512 + col] = (__bf16)v;
      }
    }
  }
}

// ---------------- V transpose: [(b*G+hl)][m][d] -> [(b*G+hl)][d][m] ----------------
__global__ void transpose_v_k(const __bf16* __restrict__ V, __bf16* __restrict__ VT) {
  __shared__ __bf16 sm[32][33];
  const int bh = blockIdx.z;
  const int mb = blockIdx.x * 32, db = blockIdx.y * 32;
  const int tx = threadIdx.x, ty = threadIdx.y;  // 32 x 8
  const __bf16* Vg = V + (size_t)bh * (2048 * 512);
  __bf16* Tg = VT + (size_t)bh * (512 * 2048);
#pragma unroll
  for (int i = 0; i < 4; i++) sm[ty + i * 8][tx] = Vg[(size_t)(mb + ty + i * 8) * 512 + db + tx];
  __syncthreads();
#pragma unroll
  for (int i = 0; i < 4; i++) Tg[(size_t)(db + ty + i * 8) * 2048 + mb + tx] = sm[tx][ty + i * 8];
}

// ---------------- causal flash attention v6 ----------------
// 8 waves x 16 q-rows (QBLK=128), KBLK=32. Block = pair legs (p, 15-p) = 68 tiles,
// 256 blocks (1/CU), xid = p*32+bh so same-bh blocks share an XCD.
// K: LDS dbuf via XOR-swizzled g2l16. V: reg-staged -> [512][40] LDS (aligned,
// conflict-free). Drain-proof: the only vmcnt(0) sits where all outstanding loads
// are one full compute-phase old; fresh prefetch issues strictly after it.
__global__ __launch_bounds__(512, 1) void flash_attn_k(
    const __bf16* __restrict__ Q, const __bf16* __restrict__ K, const __bf16* __restrict__ VT,
    __bf16* __restrict__ O, int G, int lg) {  // O: [B, M, G*512] bf16
  const int xid = blockIdx.x;        // 0 .. 32G-1
  const int bh = xid & (4 * G - 1);  // same-bh -> same XCD
  const int p = xid >> (lg + 2);     // 0..7
  const int b = bh >> lg, hl = bh & (G - 1);
  const int tid = threadIdx.x, lane = tid & 63, wid = tid >> 6;
  const int l15 = lane & 15, l4 = lane >> 4;

  __shared__ alignas(16) __bf16 Ks[2][32 * 512];  // 64KB, 3-bit XOR chunk swizzle
  __shared__ alignas(16) __bf16 Vts[512 * 40];    // 40KB, stride 80B: aligned + ~2-way banks
  __shared__ alignas(16) __bf16 Ps[8][16 * 40];   // 10KB, stride 80B

  const __bf16* Kg = K + (size_t)bh * 2048 * 512;
  const __bf16* Tg = VT + (size_t)bh * 512 * 2048;
  const float scale = 0.04419417382415922f;  // 1/sqrt(512)

  for (int pp = 0; pp < 2; ++pp) {
    const int qt = pp ? (15 - p) : p;
    const int qw = qt * 128 + wid * 16;
    const __bf16* Qg = Q + ((size_t)bh * 2048 + qw) * 512;

    bf16x8 qf[16];
#pragma unroll
    for (int c = 0; c < 16; c++)
      qf[c] = *reinterpret_cast<const bf16x8*>(Qg + l15 * 512 + c * 32 + l4 * 8);

    f32x4 acc[32];
#pragma unroll
    for (int n = 0; n < 32; n++) acc[n] = f32x4{0.f, 0.f, 0.f, 0.f};
    float mrow[4] = {-INFINITY, -INFINITY, -INFINITY, -INFINITY};
    float lrow[4] = {0.f, 0.f, 0.f, 0.f};

    const int nt = 4 * qt + 4;  // >= 4
    bf16x8 vreg[4];

    auto stageK = [&](int kt2, int bufi) {
#pragma unroll
      for (int i = 0; i < 4; i++) {
        int chunk = i * 512 + tid;
        int row = chunk >> 6, c16 = chunk & 63;
        g2l16(Kg + (size_t)(kt2 * 32 + row) * 512 + ((c16 ^ (row & 7)) << 3),
              &Ks[bufi][(i * 512 + (tid & ~63)) * 8]);
      }
    };
    auto loadV = [&](int kt2) {
#pragma unroll
      for (int i = 0; i < 4; i++) {
        int chunk = i * 512 + tid;
        vreg[i] = *reinterpret_cast<const bf16x8*>(
            Tg + (size_t)(chunk >> 2) * 2048 + kt2 * 32 + (chunk & 3) * 8);
      }
    };

    // prologue: stage tile 0
    stageK(0, 0);
    loadV(0);
    int cur = 0;

    for (int kt = 0; kt < nt; ++kt) {
      const int kb = kt * 32;

      __builtin_amdgcn_sched_barrier(0);
      __builtin_amdgcn_s_barrier();  // prev compute done everywhere: Ks[cur^1], Vts free
      __builtin_amdgcn_sched_barrier(0);
      asm volatile("s_waitcnt vmcnt(0)" ::: "memory");  // phase-old K(kt)/V(kt) landed
      __builtin_amdgcn_sched_barrier(0);

      // commit V(kt) regs -> LDS
#pragma unroll
      for (int i = 0; i < 4; i++) {
        int chunk = i * 512 + tid;
        *reinterpret_cast<bf16x8*>(&Vts[(chunk >> 2) * 40 + (chunk & 3) * 8]) = vreg[i];
      }
      __builtin_amdgcn_sched_barrier(0);
      // fresh prefetch (flies through the whole compute phase below)
      if (kt + 1 < nt) {
        stageK(kt + 1, cur ^ 1);
        loadV(kt + 1);
      }
      __builtin_amdgcn_sched_barrier(0);
      asm volatile("s_waitcnt lgkmcnt(0)" ::: "memory");  // Vts writes done
      __builtin_amdgcn_sched_barrier(0);
      __builtin_amdgcn_s_barrier();  // Vts visible to all waves
      __builtin_amdgcn_sched_barrier(0);

      // ---- compute tile kt ----
      f32x4 sv0 = f32x4{0.f, 0.f, 0.f, 0.f}, sv1 = f32x4{0.f, 0.f, 0.f, 0.f};
      const __bf16* Kl = &Ks[cur][0];
      __builtin_amdgcn_s_setprio(1);
#pragma unroll
      for (int c = 0; c < 16; c++) {
        const int off = c * 32 + l4 * 8;
        const int r0 = l15, r1 = 16 + l15;
        bf16x8 b0 = *reinterpret_cast<const bf16x8*>(Kl + r0 * 512 + (off ^ ((r0 & 7) << 3)));
        bf16x8 b1 = *reinterpret_cast<const bf16x8*>(Kl + r1 * 512 + (off ^ ((r1 & 7) << 3)));
        sv0 = MFMA16(qf[c], b0, sv0);
        sv1 = MFMA16(qf[c], b1, sv1);
      }
      __builtin_amdgcn_s_setprio(0);

      // online softmax (defer-max THR=8); mask only in the diagonal band
      const bool band = (kt >= 4 * qt);
      float mx[4];
#pragma unroll
      for (int r = 0; r < 4; r++) {
        float s0 = sv0[r] * scale;
        float s1 = sv1[r] * scale;
        if (band) {
          const int qg = qw + l4 * 4 + r;
          if (kb + l15 > qg) s0 = -INFINITY;
          if (kb + 16 + l15 > qg) s1 = -INFINITY;
        }
        sv0[r] = s0; sv1[r] = s1;
        float m_ = fmaxf(s0, s1);
        m_ = fmaxf(m_, __shfl_xor(m_, 1, 64));
        m_ = fmaxf(m_, __shfl_xor(m_, 2, 64));
        m_ = fmaxf(m_, __shfl_xor(m_, 4, 64));
        m_ = fmaxf(m_, __shfl_xor(m_, 8, 64));
        mx[r] = m_;
      }
      bool need = (mx[0] > mrow[0] + 8.f) || (mx[1] > mrow[1] + 8.f) ||
                  (mx[2] > mrow[2] + 8.f) || (mx[3] > mrow[3] + 8.f);
      if (__any(need)) {
        float alpha[4];
#pragma unroll
        for (int r = 0; r < 4; r++) {
          float mn = fmaxf(mrow[r], mx[r]);
          alpha[r] = __expf(mrow[r] - mn);
          lrow[r] *= alpha[r];
          mrow[r] = mn;
        }
#pragma unroll
        for (int n = 0; n < 32; n++) {
#pragma unroll
          for (int r = 0; r < 4; r++) acc[n][r] *= alpha[r];
        }
      }
#pragma unroll
      for (int r = 0; r < 4; r++) {
        float p0 = __expf(sv0[r] - mrow[r]);
        float p1 = __expf(sv1[r] - mrow[r]);
        float rs = p0 + p1;
        rs += __shfl_xor(rs, 1, 64);
        rs += __shfl_xor(rs, 2, 64);
        rs += __shfl_xor(rs, 4, 64);
        rs += __shfl_xor(rs, 8, 64);
        lrow[r] += rs;
        __bf16* P = &Ps[wid][0];
        P[(l4 * 4 + r) * 40 + l15] = (__bf16)p0;
        P[(l4 * 4 + r) * 40 + 16 + l15] = (__bf16)p1;
      }
      bf16x8 pf = *reinterpret_cast<const bf16x8*>(&Ps[wid][0] + l15 * 40 + l4 * 8);

      __builtin_amdgcn_s_setprio(1);
#pragma unroll
      for (int n = 0; n < 32; n++) {
        bf16x8 vb = *reinterpret_cast<const bf16x8*>(&Vts[(n * 16 + l15) * 40 + l4 * 8]);
        acc[n] = MFMA16(pf, vb, acc[n]);
      }
      __builtin_amdgcn_s_setprio(0);
      cur ^= 1;
    }

    // epilogue: O[b, qg, hl*512 + d] = acc / l
#pragma unroll
    for (int r = 0; r < 4; r++) {
      const int qg = qw + l4 * 4 + r;
      const float inv = 1.0f / lrow[r];
      __bf16* Og = O + ((size_t)(b * 2048 + qg) * (512 * G) + hl * 512);
#pragma unroll
      for (int n = 0; n < 32; n++) Og[n * 16 + l15] = (__bf16)(acc[n][r] * inv);
    }
  }
}

// ---------------- output projection (per group, accumulating) ----------------
__global__ __launch_bounds__(256, 2) void out_gemm_k(
    const __bf16* __restrict__ A, const __bf16* __restrict__ Wo,
    const float* __restrict__ bias, float* __restrict__ Y, int G, int first) {
  const int AS = 512 * G;
  const int mbase = blockIdx.x * 128, nbase = blockIdx.y * 128;
  __shared__ alignas(16) __bf16 As[128 * 64];
  __shared__ alignas(16) __bf16 Bs[128 * 64];
  const int tid = threadIdx.x;
  const int lane = tid & 63, wid = tid >> 6;
  const int wr = wid >> 1, wc = wid & 1;
  const int l15 = lane & 15, l4 = lane >> 4;

  f32x4 acc[4][4];
#pragma unroll
  for (int i = 0; i < 4; i++)
#pragma unroll
    for (int j = 0; j < 4; j++) acc[i][j] = f32x4{0.f, 0.f, 0.f, 0.f};

  const int nkt = 8 * G;
  for (int kt = 0; kt < nkt; ++kt) {
    const int kb = kt * 64;
#pragma unroll
    for (int i = 0; i < 4; i++) {
      int chunk = i * 256 + tid;
      int row = chunk >> 3, col = (chunk & 7) * 8;
      g2l16(A + (size_t)(mbase + row) * AS + kb + col, As + (i * 256 + (tid & ~63)) * 8);
    }
#pragma unroll
    for (int i = 0; i < 4; i++) {
      int chunk = i * 256 + tid;
      int row = chunk >> 3, col = (chunk & 7) * 8;
      g2l16(Wo + (size_t)(nbase + row) * 4096 + kb + col, Bs + (i * 256 + (tid & ~63)) * 8);
    }
    __syncthreads();
#pragma unroll
    for (int kk = 0; kk < 2; ++kk) {
      bf16x8 a[4], b[4];
#pragma unroll
      for (int i = 0; i < 4; i++)
        a[i] = *reinterpret_cast<const bf16x8*>(As + (wr * 64 + i * 16 + l15) * 64 + kk * 32 + l4 * 8);
#pragma unroll
      for (int j = 0; j < 4; j++)
        b[j] = *reinterpret_cast<const bf16x8*>(Bs + (wc * 64 + j * 16 + l15) * 64 + kk * 32 + l4 * 8);
#pragma unroll
      for (int i = 0; i < 4; i++)
#pragma unroll
        for (int j = 0; j < 4; j++) acc[i][j] = MFMA16(a[i], b[j], acc[i][j]);
    }
    __syncthreads();
  }

#pragma unroll
  for (int i = 0; i < 4; i++) {
#pragma unroll
    for (int j = 0; j < 4; j++) {
      const int col = nbase + wc * 64 + j * 16 + l15;
#pragma unroll
      for (int r = 0; r < 4; r++) {
        const int row = mbase + wr * 64 + i * 16 + l4 * 4 + r;
        float prev = first ? bias[col] : Y[(size_t)row * 512 + col];
        Y[(size_t)row * 512 + col] = prev + acc[i][j][r];
      }
    }
  }
}

extern "C" void kernel_launch(void* const* d_in, const int* in_sizes, int n_in,
                              void* d_out, int out_size, void* d_ws, size_t ws_size,
                              hipStream_t stream) {
  (void)in_sizes; (void)n_in; (void)out_size;
  const float* x = (const float*)d_in[0];
  const float* wq = (const float*)d_in[1];
  const float* wk = (const float*)d_in[2];
  const float* wv = (const float*)d_in[3];
  const float* wo = (const float*)d_in[4];
  const float* bo = (const float*)d_in[5];
  float* y = (float*)d_out;

  char* base = (char*)d_ws;
  size_t off = 0;
  auto alloc = [&](size_t bytes) -> void* {
    void* p = base + off;
    off += (bytes + 255) & ~(size_t)255;
    return p;
  };
  __bf16* xb = (__bf16*)alloc((size_t)8192 * 512 * 2);
  __bf16* wqb = (__bf16*)alloc((size_t)8 * 512 * 512 * 2);
  __bf16* wkb = (__bf16*)alloc((size_t)8 * 512 * 512 * 2);
  __bf16* wvb = (__bf16*)alloc((size_t)8 * 512 * 512 * 2);
  __bf16* wob = (__bf16*)alloc((size_t)512 * 4096 * 2);
  float* ct = (float*)alloc((size_t)2048 * 256 * 4);
  float* st = (float*)alloc((size_t)2048 * 256 * 4);
  const size_t persist = off;

  // choose largest head-group G with persist + 4 * (G*4*2048*512*2) <= ws_size
  int G = 0, lg = 0;
  for (int g = 8, l = 3; g >= 1; g >>= 1, --l) {
    size_t T = ((size_t)g * 4 * 2048 * 512 * 2 + 255) & ~(size_t)255;
    if (persist + 4 * T <= ws_size) { G = g; lg = l; break; }
  }
  if (G == 0) return;

  size_t T = ((size_t)G * 4 * 2048 * 512 * 2 + 255) & ~(size_t)255;
  __bf16* Qb = (__bf16*)(base + persist);
  __bf16* Kb = (__bf16*)(base + persist + T);
  __bf16* Vb = (__bf16*)(base + persist + 2 * T);
  __bf16* VTb = (__bf16*)(base + persist + 3 * T);
  __bf16* Ob = Vb;  // V dead after transpose; O ([B,M,G*512]) reuses it

  cast_bf16_k<<<4096, 256, 0, stream>>>(x, xb, 1048576);
  cast_bf16_k<<<2048, 256, 0, stream>>>(wq, wqb, 524288);
  cast_bf16_k<<<2048, 256, 0, stream>>>(wk, wkb, 524288);
  cast_bf16_k<<<2048, 256, 0, stream>>>(wv, wvb, 524288);
  cast_bf16_k<<<2048, 256, 0, stream>>>(wo, wob, 524288);
  rope_tables_k<<<2048, 256, 0, stream>>>(ct, st);

  for (int h0 = 0; h0 < 8; h0 += G) {
    qkv_gemm_k<<<dim3(64, 4, 3 * G), 256, 0, stream>>>(xb, wqb, wkb, wvb, ct, st,
                                                       Qb, Kb, Vb, G, lg, h0);
    transpose_v_k<<<dim3(64, 16, 4 * G), dim3(32, 8), 0, stream>>>(Vb, VTb);
    flash_attn_k<<<dim3(32 * G), 512, 0, stream>>>(Qb, Kb, VTb, Ob, G, lg);
    out_gemm_k<<<dim3(64, 4), 256, 0, stream>>>(Ob, wob + h0 * 512, bo, y, G, h0 == 0);
  }
}

// Round 7
// 1048.608 us; speedup vs baseline: 1.8175x; 1.2421x over previous
//
#include <hip/hip_runtime.h>
#include <hip/hip_bf16.h>
#include <math.h>

// B=4, M=2048, D=512, H=8. Heads processed in groups of G (adaptive to ws_size; G=8 on this harness).

typedef __attribute__((ext_vector_type(8))) __bf16 bf16x8;
typedef __attribute__((ext_vector_type(4))) __bf16 bf16x4;
typedef __attribute__((ext_vector_type(4))) float f32x4;

#define MFMA16(a, b, c) __builtin_amdgcn_mfma_f32_16x16x32_bf16((a), (b), (c), 0, 0, 0)

__device__ __forceinline__ void g2l16(const void* g, void* l) {
  __builtin_amdgcn_global_load_lds((const __attribute__((address_space(1))) void*)g,
                                   (__attribute__((address_space(3))) void*)l, 16, 0, 0);
}

// ---------------- cast fp32 -> bf16 ----------------
__global__ void cast_bf16_k(const float* __restrict__ in, __bf16* __restrict__ out, int n4) {
  int i = blockIdx.x * blockDim.x + threadIdx.x;
  if (i >= n4) return;
  float4 f = reinterpret_cast<const float4*>(in)[i];
  bf16x4 o;
  o.x = (__bf16)f.x; o.y = (__bf16)f.y; o.z = (__bf16)f.z; o.w = (__bf16)f.w;
  reinterpret_cast<bf16x4*>(out)[i] = o;
}

// ---------------- RoPE tables, fp32 (faithful i-1 quirk) ----------------
__global__ void rope_tables_k(float* __restrict__ ct, float* __restrict__ st) {
  int idx = blockIdx.x * 256 + threadIdx.x;  // 2048*256
  int m = idx >> 8, j = idx & 255;
  float e = (-2.0f * ((float)j - 1.0f) / 512.0f) * 13.287712379549449f;  // log2(1e4)
  float theta = exp2f(e);
  float ang = (float)m * theta;
  float s, c;
  sincosf(ang, &s, &c);
  ct[idx] = c;
  st[idx] = s;
}

// ---------------- QKV projection (round-2 proven structure): z = which*G + hl ----------------
__global__ __launch_bounds__(256, 2) void qkv_gemm_k(
    const __bf16* __restrict__ Xb,
    const __bf16* __restrict__ Wqb, const __bf16* __restrict__ Wkb, const __bf16* __restrict__ Wvb,
    const float* __restrict__ ct, const float* __restrict__ st,
    __bf16* __restrict__ Q, __bf16* __restrict__ K, __bf16* __restrict__ V,
    int G, int lg, int h0) {
  const int z = blockIdx.z;
  const int which = z >> lg, hl = z & (G - 1);
  const int h = h0 + hl;
  const __bf16* W = (which == 0 ? Wqb : which == 1 ? Wkb : Wvb) + (size_t)h * 262144;
  __bf16* Out = (which == 0 ? Q : which == 1 ? K : V);

  const int mbase = blockIdx.x * 128;
  const int nbase = blockIdx.y * 128;

  __shared__ alignas(16) __bf16 As[128 * 64];
  __shared__ alignas(16) __bf16 Bs[128 * 64];

  const int tid = threadIdx.x;
  const int lane = tid & 63, wid = tid >> 6;
  const int wr = wid >> 1, wc = wid & 1;
  const int l15 = lane & 15, l4 = lane >> 4;

  f32x4 acc[4][4];
#pragma unroll
  for (int i = 0; i < 4; i++)
#pragma unroll
    for (int j = 0; j < 4; j++) acc[i][j] = f32x4{0.f, 0.f, 0.f, 0.f};

  for (int kt = 0; kt < 8; ++kt) {
    const int kb = kt * 64;
#pragma unroll
    for (int i = 0; i < 4; i++) {
      int chunk = i * 256 + tid;
      int row = chunk >> 3, col = (chunk & 7) * 8;
      g2l16(Xb + (size_t)(mbase + row) * 512 + kb + col, As + (i * 256 + (tid & ~63)) * 8);
    }
#pragma unroll
    for (int i = 0; i < 4; i++) {
      int chunk = i * 256 + tid;
      int row = chunk >> 3, col = (chunk & 7) * 8;
      g2l16(W + (size_t)(nbase + row) * 512 + kb + col, Bs + (i * 256 + (tid & ~63)) * 8);
    }
    __syncthreads();
#pragma unroll
    for (int kk = 0; kk < 2; ++kk) {
      bf16x8 a[4], b[4];
#pragma unroll
      for (int i = 0; i < 4; i++)
        a[i] = *reinterpret_cast<const bf16x8*>(As + (wr * 64 + i * 16 + l15) * 64 + kk * 32 + l4 * 8);
#pragma unroll
      for (int j = 0; j < 4; j++)
        b[j] = *reinterpret_cast<const bf16x8*>(Bs + (wc * 64 + j * 16 + l15) * 64 + kk * 32 + l4 * 8);
#pragma unroll
      for (int i = 0; i < 4; i++)
#pragma unroll
        for (int j = 0; j < 4; j++) acc[i][j] = MFMA16(a[i], b[j], acc[i][j]);
    }
    __syncthreads();
  }

  const bool dorope = (which < 2);
#pragma unroll
  for (int i = 0; i < 4; i++) {
#pragma unroll
    for (int j = 0; j < 4; j++) {
      const int col = nbase + wc * 64 + j * 16 + l15;
#pragma unroll
      for (int r = 0; r < 4; r++) {
        const int rowg = mbase + wr * 64 + i * 16 + l4 * 4 + r;
        const int b_ = rowg >> 11, m = rowg & 2047;
        float v = acc[i][j][r];
        if (dorope) {
          float pv = __shfl_xor(v, 1, 64);  // partner column (col^1) in lane^1
          float c = ct[m * 256 + (col >> 1)];
          float s = st[m * 256 + (col >> 1)];
          v = (col & 1) ? (v * c - pv * s) : (v * c + pv * s);
        }
        Out[(size_t)((b_ * G + hl) * 2048 + m) * 512 + col] = (__bf16)v;
      }
    }
  }
}

// ---------------- V transpose: [(b*G+hl)][m][d] -> [(b*G+hl)][d][m] ----------------
__global__ void transpose_v_k(const __bf16* __restrict__ V, __bf16* __restrict__ VT) {
  __shared__ __bf16 sm[32][33];
  const int bh = blockIdx.z;
  const int mb = blockIdx.x * 32, db = blockIdx.y * 32;
  const int tx = threadIdx.x, ty = threadIdx.y;  // 32 x 8
  const __bf16* Vg = V + (size_t)bh * (2048 * 512);
  __bf16* Tg = VT + (size_t)bh * (512 * 2048);
#pragma unroll
  for (int i = 0; i < 4; i++) sm[ty + i * 8][tx] = Vg[(size_t)(mb + ty + i * 8) * 512 + db + tx];
  __syncthreads();
#pragma unroll
  for (int i = 0; i < 4; i++) Tg[(size_t)(db + ty + i * 8) * 2048 + mb + tx] = sm[tx][ty + i * 8];
}

// ---------------- causal flash attention (round-2 structure + balanced CU pairing) ----------------
// 8 waves x 16 q-rows (QBLK=128), KBLK=32. Grid 16 x 4G = 16*bhN blocks.
// Remap: L -> (half, p, bh); qt = half ? 15-p : p. Under round-robin dispatch CU c hosts
// L=c and L=c+8*bhN with complementary q-tiles -> 68 tiles per CU, 2 co-resident blocks
// (72KB LDS, VGPR 128 -> exactly 16 waves/CU). L%8 == bh%8 -> per-bh XCD locality.
__global__ __launch_bounds__(512) void flash_attn_k(
    const __bf16* __restrict__ Q, const __bf16* __restrict__ K, const __bf16* __restrict__ VT,
    __bf16* __restrict__ O, int G, int lg) {  // O: [B, M, G*512] bf16
  const int bhN = 4 * G;
  const int L = blockIdx.x + 16 * blockIdx.y;
  const int half = L / (8 * bhN);
  const int r_ = L % (8 * bhN);
  const int bh = r_ % bhN;
  const int p_ = r_ / bhN;          // 0..7
  const int qblk = half ? (15 - p_) : p_;
  const int b = bh >> lg, hl = bh & (G - 1);
  const int tid = threadIdx.x, lane = tid & 63, wid = tid >> 6;
  const int l15 = lane & 15, l4 = lane >> 4;
  const int qw = qblk * 128 + wid * 16;

  __shared__ alignas(16) __bf16 Ks[32 * 512];    // 32KB, 3-bit XOR swizzle on 16B chunks
  __shared__ alignas(16) __bf16 Vts[512 * 32];   // 32KB, 2-bit XOR swizzle
  __shared__ alignas(16) __bf16 Ps[8][16 * 32];  // 8KB, wave-private P

  const __bf16* Qg = Q + ((size_t)bh * 2048 + qw) * 512;
  const __bf16* Kg = K + (size_t)bh * 2048 * 512;
  const __bf16* Tg = VT + (size_t)bh * 512 * 2048;

  bf16x8 qf[16];
#pragma unroll
  for (int c = 0; c < 16; c++)
    qf[c] = *reinterpret_cast<const bf16x8*>(Qg + l15 * 512 + c * 32 + l4 * 8);

  f32x4 acc[32];
#pragma unroll
  for (int n = 0; n < 32; n++) acc[n] = f32x4{0.f, 0.f, 0.f, 0.f};
  float mrow[4] = {-INFINITY, -INFINITY, -INFINITY, -INFINITY};
  float lrow[4] = {0.f, 0.f, 0.f, 0.f};

  const float scale = 0.04419417382415922f;  // 1/sqrt(512)
  const int ntiles = qblk * 4 + 4;

  for (int kt = 0; kt < ntiles; ++kt) {
    const int kb = kt * 32;
#pragma unroll
    for (int i = 0; i < 4; i++) {
      int chunk = i * 512 + tid;
      int row = chunk >> 6, c16 = chunk & 63;
      g2l16(Kg + (size_t)(kb + row) * 512 + ((c16 ^ (row & 7)) << 3),
            Ks + (i * 512 + (tid & ~63)) * 8);
    }
#pragma unroll
    for (int i = 0; i < 4; i++) {
      int chunk = i * 512 + tid;
      int row = chunk >> 2, c4 = chunk & 3;
      g2l16(Tg + (size_t)row * 2048 + kb + ((c4 ^ (row & 3)) << 3),
            Vts + (i * 512 + (tid & ~63)) * 8);
    }
    __syncthreads();

    f32x4 sv0 = f32x4{0.f, 0.f, 0.f, 0.f}, sv1 = f32x4{0.f, 0.f, 0.f, 0.f};
#pragma unroll
    for (int c = 0; c < 16; c++) {
      const int off = c * 32 + l4 * 8;
      const int r0 = l15, r1 = 16 + l15;
      bf16x8 b0 = *reinterpret_cast<const bf16x8*>(Ks + r0 * 512 + (off ^ ((r0 & 7) << 3)));
      bf16x8 b1 = *reinterpret_cast<const bf16x8*>(Ks + r1 * 512 + (off ^ ((r1 & 7) << 3)));
      sv0 = MFMA16(qf[c], b0, sv0);
      sv1 = MFMA16(qf[c], b1, sv1);
    }

    float alpha[4];
#pragma unroll
    for (int r = 0; r < 4; r++) {
      const int qg = qw + l4 * 4 + r;
      float s0 = sv0[r] * scale;
      float s1 = sv1[r] * scale;
      if (kb + l15 > qg) s0 = -INFINITY;
      if (kb + 16 + l15 > qg) s1 = -INFINITY;
      float mx = fmaxf(s0, s1);
      mx = fmaxf(mx, __shfl_xor(mx, 1, 64));
      mx = fmaxf(mx, __shfl_xor(mx, 2, 64));
      mx = fmaxf(mx, __shfl_xor(mx, 4, 64));
      mx = fmaxf(mx, __shfl_xor(mx, 8, 64));
      const float mn = fmaxf(mrow[r], mx);
      const float p0 = expf(s0 - mn);
      const float p1 = expf(s1 - mn);
      const float a_ = expf(mrow[r] - mn);
      float rs = p0 + p1;
      rs += __shfl_xor(rs, 1, 64);
      rs += __shfl_xor(rs, 2, 64);
      rs += __shfl_xor(rs, 4, 64);
      rs += __shfl_xor(rs, 8, 64);
      lrow[r] = lrow[r] * a_ + rs;
      mrow[r] = mn;
      alpha[r] = a_;
      __bf16* P = &Ps[wid][0];
      P[(l4 * 4 + r) * 32 + l15] = (__bf16)p0;
      P[(l4 * 4 + r) * 32 + 16 + l15] = (__bf16)p1;
    }
#pragma unroll
    for (int n = 0; n < 32; n++) {
#pragma unroll
      for (int r = 0; r < 4; r++) acc[n][r] *= alpha[r];
    }
    bf16x8 pf = *reinterpret_cast<const bf16x8*>(&Ps[wid][0] + l15 * 32 + l4 * 8);
#pragma unroll
    for (int n = 0; n < 32; n++) {
      const int row = n * 16 + l15;
      bf16x8 vb = *reinterpret_cast<const bf16x8*>(Vts + row * 32 + ((l4 * 8) ^ ((row & 3) << 3)));
      acc[n] = MFMA16(pf, vb, acc[n]);
    }
    __syncthreads();
  }

#pragma unroll
  for (int r = 0; r < 4; r++) {
    const int qg = qw + l4 * 4 + r;
    const float inv = 1.0f / lrow[r];
    __bf16* Og = O + ((size_t)(b * 2048 + qg) * (512 * G) + hl * 512);
#pragma unroll
    for (int n = 0; n < 32; n++) Og[n * 16 + l15] = (__bf16)(acc[n][r] * inv);
  }
}

// ---------------- output projection (per group, accumulating) ----------------
__global__ __launch_bounds__(256, 2) void out_gemm_k(
    const __bf16* __restrict__ A, const __bf16* __restrict__ Wo,
    const float* __restrict__ bias, float* __restrict__ Y, int G, int first) {
  const int AS = 512 * G;
  const int mbase = blockIdx.x * 128, nbase = blockIdx.y * 128;
  __shared__ alignas(16) __bf16 As[128 * 64];
  __shared__ alignas(16) __bf16 Bs[128 * 64];
  const int tid = threadIdx.x;
  const int lane = tid & 63, wid = tid >> 6;
  const int wr = wid >> 1, wc = wid & 1;
  const int l15 = lane & 15, l4 = lane >> 4;

  f32x4 acc[4][4];
#pragma unroll
  for (int i = 0; i < 4; i++)
#pragma unroll
    for (int j = 0; j < 4; j++) acc[i][j] = f32x4{0.f, 0.f, 0.f, 0.f};

  const int nkt = 8 * G;
  for (int kt = 0; kt < nkt; ++kt) {
    const int kb = kt * 64;
#pragma unroll
    for (int i = 0; i < 4; i++) {
      int chunk = i * 256 + tid;
      int row = chunk >> 3, col = (chunk & 7) * 8;
      g2l16(A + (size_t)(mbase + row) * AS + kb + col, As + (i * 256 + (tid & ~63)) * 8);
    }
#pragma unroll
    for (int i = 0; i < 4; i++) {
      int chunk = i * 256 + tid;
      int row = chunk >> 3, col = (chunk & 7) * 8;
      g2l16(Wo + (size_t)(nbase + row) * 4096 + kb + col, Bs + (i * 256 + (tid & ~63)) * 8);
    }
    __syncthreads();
#pragma unroll
    for (int kk = 0; kk < 2; ++kk) {
      bf16x8 a[4], b[4];
#pragma unroll
      for (int i = 0; i < 4; i++)
        a[i] = *reinterpret_cast<const bf16x8*>(As + (wr * 64 + i * 16 + l15) * 64 + kk * 32 + l4 * 8);
#pragma unroll
      for (int j = 0; j < 4; j++)
        b[j] = *reinterpret_cast<const bf16x8*>(Bs + (wc * 64 + j * 16 + l15) * 64 + kk * 32 + l4 * 8);
#pragma unroll
      for (int i = 0; i < 4; i++)
#pragma unroll
        for (int j = 0; j < 4; j++) acc[i][j] = MFMA16(a[i], b[j], acc[i][j]);
    }
    __syncthreads();
  }

#pragma unroll
  for (int i = 0; i < 4; i++) {
#pragma unroll
    for (int j = 0; j < 4; j++) {
      const int col = nbase + wc * 64 + j * 16 + l15;
#pragma unroll
      for (int r = 0; r < 4; r++) {
        const int row = mbase + wr * 64 + i * 16 + l4 * 4 + r;
        float prev = first ? bias[col] : Y[(size_t)row * 512 + col];
        Y[(size_t)row * 512 + col] = prev + acc[i][j][r];
      }
    }
  }
}

extern "C" void kernel_launch(void* const* d_in, const int* in_sizes, int n_in,
                              void* d_out, int out_size, void* d_ws, size_t ws_size,
                              hipStream_t stream) {
  (void)in_sizes; (void)n_in; (void)out_size;
  const float* x = (const float*)d_in[0];
  const float* wq = (const float*)d_in[1];
  const float* wk = (const float*)d_in[2];
  const float* wv = (const float*)d_in[3];
  const float* wo = (const float*)d_in[4];
  const float* bo = (const float*)d_in[5];
  float* y = (float*)d_out;

  char* base = (char*)d_ws;
  size_t off = 0;
  auto alloc = [&](size_t bytes) -> void* {
    void* p = base + off;
    off += (bytes + 255) & ~(size_t)255;
    return p;
  };
  __bf16* xb = (__bf16*)alloc((size_t)8192 * 512 * 2);
  __bf16* wqb = (__bf16*)alloc((size_t)8 * 512 * 512 * 2);
  __bf16* wkb = (__bf16*)alloc((size_t)8 * 512 * 512 * 2);
  __bf16* wvb = (__bf16*)alloc((size_t)8 * 512 * 512 * 2);
  __bf16* wob = (__bf16*)alloc((size_t)512 * 4096 * 2);
  float* ct = (float*)alloc((size_t)2048 * 256 * 4);
  float* st = (float*)alloc((size_t)2048 * 256 * 4);
  const size_t persist = off;

  // choose largest head-group G with persist + 4 * (G*4*2048*512*2) <= ws_size
  int G = 0, lg = 0;
  for (int g = 8, l = 3; g >= 1; g >>= 1, --l) {
    size_t T = ((size_t)g * 4 * 2048 * 512 * 2 + 255) & ~(size_t)255;
    if (persist + 4 * T <= ws_size) { G = g; lg = l; break; }
  }
  if (G == 0) return;

  size_t T = ((size_t)G * 4 * 2048 * 512 * 2 + 255) & ~(size_t)255;
  __bf16* Qb = (__bf16*)(base + persist);
  __bf16* Kb = (__bf16*)(base + persist + T);
  __bf16* Vb = (__bf16*)(base + persist + 2 * T);
  __bf16* VTb = (__bf16*)(base + persist + 3 * T);
  __bf16* Ob = Vb;  // V dead after transpose; O ([B,M,G*512]) reuses it

  cast_bf16_k<<<4096, 256, 0, stream>>>(x, xb, 1048576);
  cast_bf16_k<<<2048, 256, 0, stream>>>(wq, wqb, 524288);
  cast_bf16_k<<<2048, 256, 0, stream>>>(wk, wkb, 524288);
  cast_bf16_k<<<2048, 256, 0, stream>>>(wv, wvb, 524288);
  cast_bf16_k<<<2048, 256, 0, stream>>>(wo, wob, 524288);
  rope_tables_k<<<2048, 256, 0, stream>>>(ct, st);

  for (int h0 = 0; h0 < 8; h0 += G) {
    qkv_gemm_k<<<dim3(64, 4, 3 * G), 256, 0, stream>>>(xb, wqb, wkb, wvb, ct, st,
                                                       Qb, Kb, Vb, G, lg, h0);
    transpose_v_k<<<dim3(64, 16, 4 * G), dim3(32, 8), 0, stream>>>(Vb, VTb);
    flash_attn_k<<<dim3(16, 4 * G), 512, 0, stream>>>(Qb, Kb, VTb, Ob, G, lg);
    out_gemm_k<<<dim3(64, 4), 256, 0, stream>>>(Ob, wob + h0 * 512, bo, y, G, h0 == 0);
  }
}